// Round 6
// baseline (50666.003 us; speedup 1.0000x reference)
//
#include <hip/hip_runtime.h>
#include <hip/hip_cooperative_groups.h>
#include <hip/hip_bf16.h>
#include <math.h>

namespace cg = cooperative_groups;

// Problem config (fixed)
#define BB 32      // batch
#define TT 128     // time steps
#define UU 1024    // units
#define MM 8       // memory slots
#define LL 9       // M+1
#define RR 17      // 2M+1
#define GRID 256   // persistent blocks (1 per CU -> coop launch always fits)

typedef __bf16 bf16x8 __attribute__((ext_vector_type(8)));
typedef float f32x4 __attribute__((ext_vector_type(4)));
typedef float f32x8 __attribute__((ext_vector_type(8)));

// exact 3-way bf16 split: v = x1 + x2 + x3 + O(2^-27 v)
__device__ __forceinline__ void split3(float v, __bf16* x1, __bf16* x2, __bf16* x3)
{
    __bf16 h1 = (__bf16)v;  float r = v - (float)h1;
    __bf16 h2 = (__bf16)r;  r -= (float)h2;
    *x1 = h1; *x2 = h2; *x3 = (__bf16)r;
}

__device__ __forceinline__ void split8(const f32x8 v, bf16x8& a, bf16x8& b, bf16x8& c)
{
#pragma unroll
    for (int j = 0; j < 8; ++j) {
        float f = v[j];
        __bf16 h1 = (__bf16)f; float r = f - (float)h1;
        __bf16 h2 = (__bf16)r; r -= (float)h2;
        a[j] = h1; b[j] = h2; c[j] = (__bf16)r;
    }
}

// ---- one 16-row x CG*16-col wave tile of split-6 MFMA GEMM, A fp32 [*,1024] ----
template<int CG>
__device__ __forceinline__ void tile6(
    const float* __restrict__ A,
    const __bf16* __restrict__ B1, const __bf16* __restrict__ B2,
    const __bf16* __restrict__ B3,
    const float* __restrict__ bias, float* __restrict__ C,
    int ldc, int act, int row0, int col0, int lane)
{
    int lr = lane & 15, kofs = (lane >> 4) * 8;
    const float* Ap = A + (size_t)(row0 + lr) * 1024 + kofs;
    size_t boff = (size_t)(col0 + lr) * 1024 + kofs;
    f32x4 acc[CG];
#pragma unroll
    for (int c = 0; c < CG; ++c) acc[c] = (f32x4){0.f, 0.f, 0.f, 0.f};

    for (int k = 0; k < 1024; k += 32) {
        f32x8 af = *(const f32x8*)(Ap + k);
        bf16x8 a1, a2, a3;
        split8(af, a1, a2, a3);
#pragma unroll
        for (int c = 0; c < CG; ++c) {
            size_t o = boff + (size_t)c * 16 * 1024 + k;
            bf16x8 b1 = *(const bf16x8*)(B1 + o);
            bf16x8 b2 = *(const bf16x8*)(B2 + o);
            bf16x8 b3 = *(const bf16x8*)(B3 + o);
            acc[c] = __builtin_amdgcn_mfma_f32_16x16x32_bf16(a1, b1, acc[c], 0, 0, 0);
            acc[c] = __builtin_amdgcn_mfma_f32_16x16x32_bf16(a1, b2, acc[c], 0, 0, 0);
            acc[c] = __builtin_amdgcn_mfma_f32_16x16x32_bf16(a2, b1, acc[c], 0, 0, 0);
            acc[c] = __builtin_amdgcn_mfma_f32_16x16x32_bf16(a1, b3, acc[c], 0, 0, 0);
            acc[c] = __builtin_amdgcn_mfma_f32_16x16x32_bf16(a2, b2, acc[c], 0, 0, 0);
            acc[c] = __builtin_amdgcn_mfma_f32_16x16x32_bf16(a3, b1, acc[c], 0, 0, 0);
        }
    }

    int r0 = row0 + (lane >> 4) * 4;
#pragma unroll
    for (int c = 0; c < CG; ++c) {
        int col = col0 + c * 16 + lr;
        float bv = bias ? bias[col] : 0.f;
#pragma unroll
        for (int r = 0; r < 4; ++r) {
            float v = acc[c][r] + bv;
            if (act == 1) {  // gelu (tanh approx, JAX default)
                float x = v;
                float t = tanhf(0.7978845608028654f * (x + 0.044715f * x * x * x));
                v = 0.5f * x * (1.f + t);
            }
            C[(size_t)(r0 + r) * ldc + col] = v;
        }
    }
}

// standalone split6 GEMM: grid (N/128, M/32), block 256
__global__ __launch_bounds__(256) void gemm6(
    const float* __restrict__ A,
    const __bf16* __restrict__ B1, const __bf16* __restrict__ B2,
    const __bf16* __restrict__ B3,
    const float* __restrict__ bias, float* __restrict__ C, int ldc, int act)
{
    int wave = threadIdx.x >> 6, lane = threadIdx.x & 63;
    int row0 = blockIdx.y * 32 + (wave >> 1) * 16;
    int col0 = blockIdx.x * 128 + (wave & 1) * 64;
    tile6<4>(A, B1, B2, B3, bias, C, ldc, act, row0, col0, lane);
}

// ---------- weight transpose + 3-way split: out[N,1024] planes = in[1024,N]^T
__global__ __launch_bounds__(256) void transpose_split(
    const float* __restrict__ in,
    __bf16* __restrict__ o1, __bf16* __restrict__ o2, __bf16* __restrict__ o3,
    int N)
{
    __shared__ float t[32][33];
    int tx = threadIdx.x & 31, ty = threadIdx.x >> 5;
    int k0 = blockIdx.y * 32, n0 = blockIdx.x * 32;
#pragma unroll
    for (int i = 0; i < 4; ++i)
        t[ty + i * 8][tx] = in[(size_t)(k0 + ty + i * 8) * N + n0 + tx];
    __syncthreads();
#pragma unroll
    for (int i = 0; i < 4; ++i) {
        float v = t[tx][ty + i * 8];
        size_t off = (size_t)(n0 + ty + i * 8) * 1024 + k0 + tx;
        split3(v, o1 + off, o2 + off, o3 + off);
    }
}

// ---------------- tiny fp32 GEMM (one-time rproj) ----------------
#define BKK 16
__global__ __launch_bounds__(256) void gemm_f32(
    const float* __restrict__ A, const float* __restrict__ B,
    float* __restrict__ C, int M, int N, int K)
{
    __shared__ float As[BKK][65];
    __shared__ float Bs[BKK][64];
    int tid = threadIdx.x;
    int row0 = blockIdx.y * 64, col0 = blockIdx.x * 64;
    int ty = tid >> 4, tx = tid & 15;
    float acc[4][4];
#pragma unroll
    for (int i = 0; i < 4; ++i)
#pragma unroll
        for (int j = 0; j < 4; ++j) acc[i][j] = 0.f;
    for (int k0 = 0; k0 < K; k0 += BKK) {
        {
            int r = tid >> 2, kv = (tid & 3) * 4;
            float4 v = make_float4(0.f, 0.f, 0.f, 0.f);
            int gr = row0 + r;
            if (gr < M) v = *(const float4*)(A + (size_t)gr * K + k0 + kv);
            As[kv + 0][r] = v.x; As[kv + 1][r] = v.y;
            As[kv + 2][r] = v.z; As[kv + 3][r] = v.w;
        }
        {
            int r = tid >> 4, cv = (tid & 15) * 4;
            float4 v = *(const float4*)(B + (size_t)(k0 + r) * N + col0 + cv);
            *(float4*)&Bs[r][cv] = v;
        }
        __syncthreads();
#pragma unroll
        for (int kk = 0; kk < BKK; ++kk) {
            float a[4], b[4];
#pragma unroll
            for (int j = 0; j < 4; ++j) a[j] = As[kk][ty * 4 + j];
#pragma unroll
            for (int j = 0; j < 4; ++j) b[j] = Bs[kk][tx * 4 + j];
#pragma unroll
            for (int i = 0; i < 4; ++i)
#pragma unroll
                for (int j = 0; j < 4; ++j) acc[i][j] += a[i] * b[j];
        }
        __syncthreads();
    }
#pragma unroll
    for (int i = 0; i < 4; ++i) {
        int gr = row0 + ty * 4 + i;
        if (gr >= M) continue;
#pragma unroll
        for (int j = 0; j < 4; ++j)
            C[(size_t)gr * N + col0 + tx * 4 + j] = acc[i][j];
    }
}

// ---------------- relative embedding table ----------------
__global__ void relemb_kernel(float* __restrict__ tab)
{
    int p = blockIdx.x;
    float pv = (float)(p - MM);
    for (int i = threadIdx.x; i < UU; i += blockDim.x) {
        float expo = (float)(i & ~1) * (1.0f / (float)UU);
        float scale = exp2f(-expo * 13.287712379549449f);  // 10000^-expo
        float ang = pv * scale;
        tab[p * UU + i] = (i & 1) ? cosf(ang) : sinf(ang);
    }
}

// ---------------- init mp ----------------
__global__ void init_mp(const float* __restrict__ xp_all, float* __restrict__ mp)
{
    int row = blockIdx.x;                 // 0..287
    int b = row / LL, l = row % LL;
    for (int u = threadIdx.x; u < UU; u += blockDim.x)
        mp[(size_t)row * UU + u] = (l == MM) ? xp_all[((size_t)b * TT) * UU + u] : 0.f;
}

// ================= shared phase bodies (used by coop kernel AND fallback) ====
struct ScanArgs {
    const float* xp_all;   // [4096,1024]
    const float* gx_all;   // [4096,2048]
    const float* rproj;    // [17,1024]
    const float* b1;       // [5120]
    const float* bm;       // [2048]
    const float* gam;      // [2048]
    const float* bet;      // [2048]
    const __bf16 *W1a, *W1b, *W1c;   // [5120,1024]
    const __bf16 *Wma, *Wmb, *Wmc;   // [2048,1024]
    float* mp;     // [288,1024]
    float* qkvg;   // [288,5120]
    float* a1;     // [288,1024]
    float* hbuf;   // [288,1024]
    float* m2;     // [288,1024]
    float* out;    // [32,128,1024]
};

// attention + LN1 for batch element b. 256 threads. sA: [LL][UU] shared.
__device__ __forceinline__ void attn_body(const ScanArgs& a, int b, int tid,
                                          float (*sA)[UU], float* red)
{
    int wave = tid >> 6, lane = tid & 63;
    for (int hh = 0; hh < 4; ++hh) {
        int hd = wave + hh * 4;
        const float* base = a.qkvg + (size_t)b * LL * 5120 + hd * 64 + lane;
        float q[LL], k[LL], v[LL], r[RR];
#pragma unroll
        for (int l = 0; l < LL; ++l) {
            q[l] = base[l * 5120];
            k[l] = base[l * 5120 + 1024];
            v[l] = base[l * 5120 + 2048];
        }
#pragma unroll
        for (int rp = 0; rp < RR; ++rp)
            r[rp] = a.rproj[rp * UU + hd * 64 + lane];
#pragma unroll
        for (int qr = 0; qr < LL; ++qr) {
            float sc[LL];
#pragma unroll
            for (int kr = 0; kr < LL; ++kr) {
                float prod = q[qr] * (k[kr] + r[qr - kr + MM]);
#pragma unroll
                for (int o = 32; o > 0; o >>= 1) prod += __shfl_xor(prod, o);
                sc[kr] = prod * 0.125f;
            }
            float m = sc[0];
#pragma unroll
            for (int kr = 1; kr < LL; ++kr) m = fmaxf(m, sc[kr]);
            float s = 0.f;
#pragma unroll
            for (int kr = 0; kr < LL; ++kr) { sc[kr] = expf(sc[kr] - m); s += sc[kr]; }
            float inv = 1.0f / s;
            float acc = 0.f;
#pragma unroll
            for (int kr = 0; kr < LL; ++kr) acc += sc[kr] * v[kr];
            sA[qr][hd * 64 + lane] = acc * inv;
        }
    }
    __syncthreads();
    int wave2 = tid >> 6, lane2 = tid & 63;
    for (int l = 0; l < LL; ++l) {
        size_t row = (size_t)(b * LL + l);
        float x[4];
        float s = 0.f, ss = 0.f;
#pragma unroll
        for (int j = 0; j < 4; ++j) {
            int u = tid + j * 256;
            x[j] = a.mp[row * UU + u] + sA[l][u];
            s += x[j]; ss += x[j] * x[j];
        }
#pragma unroll
        for (int o = 32; o > 0; o >>= 1) { s += __shfl_xor(s, o); ss += __shfl_xor(ss, o); }
        if (lane2 == 0) { red[wave2 * 2] = s; red[wave2 * 2 + 1] = ss; }
        __syncthreads();
        float S = 0.f, SS = 0.f;
#pragma unroll
        for (int w = 0; w < 4; ++w) { S += red[w * 2]; SS += red[w * 2 + 1]; }
        __syncthreads();
        float mean = S * (1.0f / UU);
        float var = SS * (1.0f / UU) - mean * mean;
        float rstd = rsqrtf(var + 1e-6f);
#pragma unroll
        for (int j = 0; j < 4; ++j) {
            int u = tid + j * 256;
            a.a1[row * UU + u] = (x[j] - mean) * rstd * a.gam[u] + a.bet[u];
        }
    }
}

// LN2 + gates + memory update + output for row. 256 threads.
__device__ __forceinline__ void finalize_body(const ScanArgs& a, int row, int t,
                                              int tid, float* red)
{
    int b = row / LL, l = row % LL;
    int wave = tid >> 6, lane = tid & 63;
    float x[4];
    float s = 0.f, ss = 0.f;
#pragma unroll
    for (int j = 0; j < 4; ++j) {
        int u = tid + j * 256;
        x[j] = a.a1[(size_t)row * UU + u] + a.m2[(size_t)row * UU + u];
        s += x[j]; ss += x[j] * x[j];
    }
#pragma unroll
    for (int o = 32; o > 0; o >>= 1) { s += __shfl_xor(s, o); ss += __shfl_xor(ss, o); }
    if (lane == 0) { red[wave * 2] = s; red[wave * 2 + 1] = ss; }
    __syncthreads();
    float S = 0.f, SS = 0.f;
#pragma unroll
    for (int w = 0; w < 4; ++w) { S += red[w * 2]; SS += red[w * 2 + 1]; }
    __syncthreads();
    float mean = S * (1.0f / UU);
    float rstd = rsqrtf(SS * (1.0f / UU) - mean * mean + 1e-6f);

    size_t gxoff = ((size_t)b * TT + t) * 2048;
    size_t grow = (size_t)row * 5120 + 3072;
#pragma unroll
    for (int j = 0; j < 4; ++j) {
        int u = tid + j * 256;
        float cand = (x[j] - mean) * rstd * a.gam[1024 + u] + a.bet[1024 + u];
        float tc = tanhf(cand);
        float gi = a.gx_all[gxoff + u]        + a.qkvg[grow + u];
        float gf = a.gx_all[gxoff + 1024 + u] + a.qkvg[grow + 1024 + u];
        float ig = fminf(fmaxf(0.2f * gi + 0.5f, 0.f), 1.f);
        float fg = fminf(fmaxf(0.2f * (gf + 1.0f) + 0.5f, 0.f), 1.f);
        size_t off = (size_t)row * UU + u;
        float nmp = fg * a.mp[off] + ig * tc;
        if (l < MM) {
            a.mp[off] = nmp;
        } else {
            a.out[((size_t)b * TT + t) * UU + u] = nmp;
            if (t + 1 < TT)
                a.mp[off] = a.xp_all[((size_t)b * TT + t + 1) * UU + u];
        }
    }
}

// ---------------- persistent cooperative scan kernel ----------------
__global__ __launch_bounds__(256) void scan_kernel(ScanArgs a)
{
    cg::grid_group grid = cg::this_grid();
    int bid = blockIdx.x;
    int tid = threadIdx.x, wave = tid >> 6, lane = tid & 63;
    __shared__ float sA[LL][UU];
    __shared__ float red[8];

    for (int t = 0; t < TT; ++t) {
        // phase A: qkvg = mp @ [Wa|Wr] + b1
        for (int tile = bid; tile < 360; tile += GRID) {
            int colT = tile % 40, rowT = tile / 40;
            tile6<4>(a.mp, a.W1a, a.W1b, a.W1c, a.b1, a.qkvg, 5120, 0,
                     rowT * 32 + (wave >> 1) * 16,
                     colT * 128 + (wave & 1) * 64, lane);
        }
        grid.sync();
        // phase B: attention + LN1
        if (bid < BB) attn_body(a, bid, tid, sA, red);
        grid.sync();
        // phase D: h = gelu(a1 @ Wm[:,:U] + bm[:U])
        for (int tile = bid; tile < 72; tile += GRID) {
            int colT = tile % 8, rowT = tile / 8;
            tile6<4>(a.a1, a.Wma, a.Wmb, a.Wmc, a.bm, a.hbuf, UU, 1,
                     rowT * 32 + (wave >> 1) * 16,
                     colT * 128 + (wave & 1) * 64, lane);
        }
        grid.sync();
        // phase E: m2 = h @ Wm[:,U:] + bm[U:]
        for (int tile = bid; tile < 72; tile += GRID) {
            int colT = tile % 8, rowT = tile / 8;
            tile6<4>(a.hbuf, a.Wma + (size_t)1024 * 1024, a.Wmb + (size_t)1024 * 1024,
                     a.Wmc + (size_t)1024 * 1024, a.bm + 1024, a.m2, UU, 0,
                     rowT * 32 + (wave >> 1) * 16,
                     colT * 128 + (wave & 1) * 64, lane);
        }
        grid.sync();
        // phase F: LN2 + gates + memory update
        for (int row = bid; row < BB * LL; row += GRID)
            finalize_body(a, row, t, tid, red);
        grid.sync();
    }
}

// ---------------- fallback per-phase kernels (identical numerics) ----------
__global__ __launch_bounds__(256) void attn_k(ScanArgs a)
{
    __shared__ float sA[LL][UU];
    __shared__ float red[8];
    attn_body(a, blockIdx.x, threadIdx.x, sA, red);
}

__global__ __launch_bounds__(256) void finalize_k(ScanArgs a, int t)
{
    __shared__ float red[8];
    finalize_body(a, blockIdx.x, t, threadIdx.x, red);
}

// ---------------- host launcher ----------------
extern "C" void kernel_launch(void* const* d_in, const int* in_sizes, int n_in,
                              void* d_out, int out_size, void* d_ws, size_t ws_size,
                              hipStream_t stream)
{
    const float* x    = (const float*)d_in[0];
    const float* Wi   = (const float*)d_in[1];
    const float* bi   = (const float*)d_in[2];
    const float* Wg   = (const float*)d_in[3];
    const float* Wr   = (const float*)d_in[4];
    const float* br   = (const float*)d_in[5];
    const float* Wa   = (const float*)d_in[6];
    const float* ba   = (const float*)d_in[7];
    const float* Wm   = (const float*)d_in[8];
    const float* bm   = (const float*)d_in[9];
    const float* gam  = (const float*)d_in[10];
    const float* bet  = (const float*)d_in[11];
    const float* Wrel = (const float*)d_in[12];
    float* out = (float*)d_out;

    // ---- workspace layout ----
    char* w = (char*)d_ws;
    float*  xp_all = (float*)w;  w += (size_t)BB*TT*UU*4;
    float*  gx_all = (float*)w;  w += (size_t)BB*TT*2048*4;
    size_t W1N = (size_t)5120 * 1024, WMN = (size_t)2048 * 1024;
    __bf16* W1a = (__bf16*)w;    w += W1N*2;
    __bf16* W1b = (__bf16*)w;    w += W1N*2;
    __bf16* W1c = (__bf16*)w;    w += W1N*2;
    __bf16* Wma = (__bf16*)w;    w += WMN*2;
    __bf16* Wmb = (__bf16*)w;    w += WMN*2;
    __bf16* Wmc = (__bf16*)w;    w += WMN*2;
    float*  b1    = (float*)w;   w += 5120*4;
    float*  tab   = (float*)w;   w += RR*UU*4;
    float*  rproj = (float*)w;   w += RR*UU*4;
    float*  mp    = (float*)w;   w += (size_t)BB*LL*UU*4;
    // scan scratch (aliased by prep-only Wi/Wg planes)
    char* sbase = w;
    float*  qkvg  = (float*)w;   w += (size_t)BB*LL*5120*4;
    float*  a1    = (float*)w;   w += (size_t)BB*LL*UU*4;
    float*  hbuf  = (float*)w;   w += (size_t)BB*LL*UU*4;
    float*  m2    = (float*)w;   w += (size_t)BB*LL*UU*4;
    __bf16* Wia = (__bf16*)sbase;
    __bf16* Wib = Wia + (size_t)1024 * 1024;
    __bf16* Wic = Wib + (size_t)1024 * 1024;
    __bf16* Wga = Wic + (size_t)1024 * 1024;
    __bf16* Wgb = Wga + (size_t)2048 * 1024;
    __bf16* Wgc = Wgb + (size_t)2048 * 1024;

    // ---- one-time prep ----
    relemb_kernel<<<RR, 256, 0, stream>>>(tab);
    gemm_f32<<<dim3(UU / 64, 1), 256, 0, stream>>>(tab, Wrel, rproj, RR, UU, UU);
    transpose_split<<<dim3(3072 / 32, 32), 256, 0, stream>>>(Wa, W1a, W1b, W1c, 3072);
    transpose_split<<<dim3(2048 / 32, 32), 256, 0, stream>>>(
        Wr, W1a + (size_t)3072 * 1024, W1b + (size_t)3072 * 1024,
        W1c + (size_t)3072 * 1024, 2048);
    transpose_split<<<dim3(2048 / 32, 32), 256, 0, stream>>>(Wm, Wma, Wmb, Wmc, 2048);
    transpose_split<<<dim3(1024 / 32, 32), 256, 0, stream>>>(Wi, Wia, Wib, Wic, 1024);
    transpose_split<<<dim3(2048 / 32, 32), 256, 0, stream>>>(Wg, Wga, Wgb, Wgc, 2048);
    hipMemcpyAsync(b1, ba, 3072 * sizeof(float), hipMemcpyDeviceToDevice, stream);
    hipMemcpyAsync(b1 + 3072, br, 2048 * sizeof(float), hipMemcpyDeviceToDevice, stream);
    gemm6<<<dim3(UU / 128, (BB * TT) / 32), 256, 0, stream>>>(
        x, Wia, Wib, Wic, bi, xp_all, UU, 0);
    gemm6<<<dim3(2048 / 128, (BB * TT) / 32), 256, 0, stream>>>(
        x, Wga, Wgb, Wgc, nullptr, gx_all, 2048, 0);
    init_mp<<<BB * LL, 256, 0, stream>>>(xp_all, mp);

    // ---- scan ----
    ScanArgs sa;
    sa.xp_all = xp_all; sa.gx_all = gx_all; sa.rproj = rproj; sa.b1 = b1;
    sa.bm = bm; sa.gam = gam; sa.bet = bet;
    sa.W1a = W1a; sa.W1b = W1b; sa.W1c = W1c;
    sa.Wma = Wma; sa.Wmb = Wmb; sa.Wmc = Wmc;
    sa.mp = mp; sa.qkvg = qkvg; sa.a1 = a1; sa.hbuf = hbuf; sa.m2 = m2;
    sa.out = out;
    void* kargs[] = { (void*)&sa };
    hipError_t ce = hipLaunchCooperativeKernel((void*)scan_kernel, dim3(GRID),
                                               dim3(256), kargs, 0, stream);
    if (ce != hipSuccess) {
        // fallback: same phases as separate dispatches (identical numerics)
        for (int t = 0; t < TT; ++t) {
            gemm6<<<dim3(40, 9), 256, 0, stream>>>(mp, W1a, W1b, W1c, b1,
                                                   qkvg, 5120, 0);
            attn_k<<<BB, 256, 0, stream>>>(sa);
            gemm6<<<dim3(8, 9), 256, 0, stream>>>(a1, Wma, Wmb, Wmc, bm,
                                                  hbuf, UU, 1);
            gemm6<<<dim3(8, 9), 256, 0, stream>>>(hbuf, Wma + (size_t)1024 * 1024,
                                                  Wmb + (size_t)1024 * 1024,
                                                  Wmc + (size_t)1024 * 1024,
                                                  bm + 1024, m2, UU, 0);
            finalize_k<<<BB * LL, 256, 0, stream>>>(sa, t);
        }
    }
}